// Round 7
// baseline (198.018 us; speedup 1.0000x reference)
//
#include <hip/hip_runtime.h>
#include <math.h>

#define B 256
#define D 512
#define S 196
#define SQ 49    // float4 quads per 196-float row
#define NCH 8    // row-chunks of 64
#define NINST 49 // 1KB DMA instructions per 64-row chunk (64*784B = 49*1024B)

// Async global->LDS DMA, 16B per lane, 1KB per wave-instruction. No VGPR
// destination -> queue depth independent of register allocator (which
// collapsed every explicit load batch in R2-R4). lds base must be
// wave-uniform; each lane supplies g + lane*16B.
__device__ __forceinline__ void stage1k(const float* __restrict__ g,
                                        float* lds_base, int lane) {
    __builtin_amdgcn_global_load_lds(
        (const __attribute__((address_space(1))) void*)(g + 4 * lane),
        (__attribute__((address_space(3))) void*)lds_base,
        16, 0, 0);
}

// ---------------- K1: gpart[(b*8+ce)*D + d] = sum_{e in chunk ce} u[b,e]*W[e,d]
// u = ctrl*w_attn. Grid 256 (ce x b-octet) x 256 thr; W row loaded once,
// reused for 8 batches from registers (W L2 traffic 32 MB).
__global__ __launch_bounds__(256) void k_gemm(const float* __restrict__ ctrl,
                                              const float* __restrict__ w_attn,
                                              const float* __restrict__ W,
                                              float* __restrict__ gpart) {
    __shared__ float u_s[64][8];
    const int ce = blockIdx.x >> 5;
    const int b0 = (blockIdx.x & 31) * 8;
    const int t = threadIdx.x;
#pragma unroll
    for (int k = t; k < 512; k += 256) {
        const int j = k & 7, el = k >> 3;
        const int e = ce * 64 + el;
        u_s[el][j] = ctrl[(b0 + j) * D + e] * w_attn[e];
    }
    __syncthreads();
    float a0[8], a1[8];
#pragma unroll
    for (int j = 0; j < 8; ++j) { a0[j] = 0.f; a1[j] = 0.f; }
    for (int e0 = 0; e0 < 64; e0 += 4) {
        float w0[4], w1[4];
#pragma unroll
        for (int i = 0; i < 4; ++i) {
            const int e = ce * 64 + e0 + i;
            w0[i] = W[e * D + t];
            w1[i] = W[e * D + t + 256];
        }
#pragma unroll
        for (int i = 0; i < 4; ++i) {
            const float4 ua = *(const float4*)&u_s[e0 + i][0];
            const float4 ub = *(const float4*)&u_s[e0 + i][4];
            a0[0] += ua.x * w0[i]; a0[1] += ua.y * w0[i];
            a0[2] += ua.z * w0[i]; a0[3] += ua.w * w0[i];
            a0[4] += ub.x * w0[i]; a0[5] += ub.y * w0[i];
            a0[6] += ub.z * w0[i]; a0[7] += ub.w * w0[i];
            a1[0] += ua.x * w1[i]; a1[1] += ua.y * w1[i];
            a1[2] += ua.z * w1[i]; a1[3] += ua.w * w1[i];
            a1[4] += ub.x * w1[i]; a1[5] += ub.y * w1[i];
            a1[6] += ub.z * w1[i]; a1[7] += ub.w * w1[i];
        }
    }
#pragma unroll
    for (int j = 0; j < 8; ++j) {
        gpart[((size_t)(b0 + j) * NCH + ce) * D + t]       = a0[j];
        gpart[((size_t)(b0 + j) * NCH + ce) * D + t + 256] = a1[j];
    }
}

// ---------------- K2: p-head + partial logits. Grid B*8 = 2048 x 256 thr.
// Staging: 49 async 1KB DMAs (wave w takes inst w, w+4, ...) -> ~12
// queued DMAs/wave, ~150KB in flight per CU at 3 blocks/CU. p-head runs
// under the DMA latency; __syncthreads drains vmcnt (m97 semantics).
__global__ __launch_bounds__(256) void k_logits(const float* __restrict__ kb,
                                                const float* __restrict__ gpart,
                                                const float* __restrict__ mem,
                                                const float* __restrict__ ctrl,
                                                const float* __restrict__ w_attn,
                                                float* __restrict__ rai_part) {
    __shared__ float kb_s[64 * S];      // 50176 B
    __shared__ float p_s[64];
    __shared__ float part[4][S];
    const int bid = blockIdx.x;
    const int b = bid >> 3, c = bid & 7;
    const int t = threadIdx.x;
    const int w = t >> 6, l = t & 63;
    const float* base = kb + (size_t)b * D * S + (size_t)c * 64 * S;

    // issue async staging first
    for (int inst = w; inst < NINST; inst += 4)
        stage1k(base + inst * 256, &kb_s[inst * 256], l);

    // p-head while DMAs fly: p[d] = mem*sum_ce(gpart) + ctrl*w_attn
    // (b_concat dropped: softmax-shift-invariant)
    if (t < 64) {
        const int d = c * 64 + t;
        float s = 0.f;
#pragma unroll
        for (int ce = 0; ce < NCH; ++ce)
            s += gpart[((size_t)b * NCH + ce) * D + d];
        p_s[t] = mem[b * D + d] * s + ctrl[b * D + d] * w_attn[d];
    }
    __syncthreads();   // drains vmcnt(0) + lds writes

    if (l < SQ) {
        float4 acc = {0.f, 0.f, 0.f, 0.f};
#pragma unroll
        for (int i = 0; i < 16; ++i) {
            const int r = w * 16 + i;
            const float4 v = *(const float4*)&kb_s[r * S + 4 * l];
            const float pv = p_s[r];
            acc.x += pv * v.x; acc.y += pv * v.y;
            acc.z += pv * v.z; acc.w += pv * v.w;
        }
        *(float4*)&part[w][4 * l] = acc;
    }
    __syncthreads();
    if (t < S)
        rai_part[(size_t)bid * S + t] = (part[0][t] + part[1][t]) + (part[2][t] + part[3][t]);
}

// ---------------- K3: softmax-head + weighted sum. Grid B*8 = 2048 x 256.
// Staging DMAs issued first (kb re-read is L2/L3-hot), softmax head overlaps
// the DMA latency, then compute entirely from LDS.
__global__ __launch_bounds__(256) void k_wsum(const float* __restrict__ kb,
                                              const float* __restrict__ rai_part,
                                              float* __restrict__ out) {
    __shared__ float kb_s[64 * S];      // 50176 B
    __shared__ float rvi_s[S];
    __shared__ float redm[4], reds[4];
    const int bid = blockIdx.x;
    const int b = bid >> 3, c = bid & 7;
    const int t = threadIdx.x;
    const int w = t >> 6, l = t & 63;
    const float* base = kb + (size_t)b * D * S + (size_t)c * 64 * S;

    for (int inst = w; inst < NINST; inst += 4)
        stage1k(base + inst * 256, &kb_s[inst * 256], l);

    // softmax head (L2-hot rai_part) under DMA latency
    float rai = -INFINITY;
    if (t < S) {
        float v = 0.f;
#pragma unroll
        for (int k = 0; k < NCH; ++k)
            v += rai_part[((size_t)b * NCH + k) * S + t];
        rai = v;
    }
    float m = rai;
#pragma unroll
    for (int o = 1; o < 64; o <<= 1) m = fmaxf(m, __shfl_xor(m, o, 64));
    if (l == 0) redm[w] = m;
    __syncthreads();
    m = fmaxf(fmaxf(redm[0], redm[1]), fmaxf(redm[2], redm[3]));
    float ex = (t < S) ? __expf(rai - m) : 0.f;
    float sm = ex;
#pragma unroll
    for (int o = 1; o < 64; o <<= 1) sm += __shfl_xor(sm, o, 64);
    if (l == 0) reds[w] = sm;
    __syncthreads();   // also drains staging vmcnt
    const float li = (reds[0] + reds[1]) + (reds[2] + reds[3]);
    if (t < S) rvi_s[t] = ex / li;
    __syncthreads();

    float4 rv = {0.f, 0.f, 0.f, 0.f};
    if (l < SQ) rv = *(const float4*)&rvi_s[4 * l];
#pragma unroll
    for (int i = 0; i < 16; ++i) {
        const int r = w * 16 + i;
        float a = 0.f;
        if (l < SQ) {
            const float4 v = *(const float4*)&kb_s[r * S + 4 * l];
            a = rv.x * v.x + rv.y * v.y + rv.z * v.z + rv.w * v.w;
        }
#pragma unroll
        for (int o = 1; o < 64; o <<= 1) a += __shfl_xor(a, o, 64);
        if (l == 0) out[(size_t)b * D + c * 64 + r] = a;
    }
}

extern "C" void kernel_launch(void* const* d_in, const int* in_sizes, int n_in,
                              void* d_out, int out_size, void* d_ws, size_t ws_size,
                              hipStream_t stream) {
    const float* mem  = (const float*)d_in[0];  // [B, d]
    const float* ctrl = (const float*)d_in[1];  // [B, d]
    const float* kb   = (const float*)d_in[2];  // [B, d, S]
    const float* W    = (const float*)d_in[3];  // [d, d]
    // d_in[4] = b_concat: softmax-invariant, unused
    const float* wat  = (const float*)d_in[5];  // [d]
    float* out = (float*)d_out;                 // [B, d]

    float* gpart    = (float*)d_ws;                      // B*8*D = 4 MB
    float* rai_part = gpart + (size_t)B * NCH * D;       // 2048*S = 1.6 MB

    k_gemm  <<<256,     256, 0, stream>>>(ctrl, wat, W, gpart);
    k_logits<<<B * NCH, 256, 0, stream>>>(kb, gpart, mem, ctrl, wat, rai_part);
    k_wsum  <<<B * NCH, 256, 0, stream>>>(kb, rai_part, out);
}

// Round 8
// 189.644 us; speedup vs baseline: 1.0442x; 1.0442x over previous
//
#include <hip/hip_runtime.h>
#include <math.h>

#define B 256
#define D 512
#define S 196
#define SQ 49    // float4 quads per 196-float row
#define NCH 8    // row-chunks of 64

// ---------------- K1: gpart[(b*8+ce)*D + d] = sum_{e in chunk ce} u[b,e]*W[e,d]
// u = ctrl*w_attn. Grid 256 (ce x b-octet) x 256 thr; W row loaded once,
// reused for 8 batches from registers (W L2 traffic 32 MB).
__global__ __launch_bounds__(256) void k_gemm(const float* __restrict__ ctrl,
                                              const float* __restrict__ w_attn,
                                              const float* __restrict__ W,
                                              float* __restrict__ gpart) {
    __shared__ float u_s[64][8];
    const int ce = blockIdx.x >> 5;
    const int b0 = (blockIdx.x & 31) * 8;
    const int t = threadIdx.x;
#pragma unroll
    for (int k = t; k < 512; k += 256) {
        const int j = k & 7, el = k >> 3;
        const int e = ce * 64 + el;
        u_s[el][j] = ctrl[(b0 + j) * D + e] * w_attn[e];
    }
    __syncthreads();
    float a0[8], a1[8];
#pragma unroll
    for (int j = 0; j < 8; ++j) { a0[j] = 0.f; a1[j] = 0.f; }
    for (int e0 = 0; e0 < 64; e0 += 4) {
        float w0[4], w1[4];
#pragma unroll
        for (int i = 0; i < 4; ++i) {
            const int e = ce * 64 + e0 + i;
            w0[i] = W[e * D + t];
            w1[i] = W[e * D + t + 256];
        }
#pragma unroll
        for (int i = 0; i < 4; ++i) {
            const float4 ua = *(const float4*)&u_s[e0 + i][0];
            const float4 ub = *(const float4*)&u_s[e0 + i][4];
            a0[0] += ua.x * w0[i]; a0[1] += ua.y * w0[i];
            a0[2] += ua.z * w0[i]; a0[3] += ua.w * w0[i];
            a0[4] += ub.x * w0[i]; a0[5] += ub.y * w0[i];
            a0[6] += ub.z * w0[i]; a0[7] += ub.w * w0[i];
            a1[0] += ua.x * w1[i]; a1[1] += ua.y * w1[i];
            a1[2] += ua.z * w1[i]; a1[3] += ua.w * w1[i];
            a1[4] += ub.x * w1[i]; a1[5] += ub.y * w1[i];
            a1[6] += ub.z * w1[i]; a1[7] += ub.w * w1[i];
        }
    }
#pragma unroll
    for (int j = 0; j < 8; ++j) {
        gpart[((size_t)(b0 + j) * NCH + ce) * D + t]       = a0[j];
        gpart[((size_t)(b0 + j) * NCH + ce) * D + t + 256] = a1[j];
    }
}

// ---------------- K2: p-head + partial logits. Grid B*8 = 2048 x 256 thr.
// __launch_bounds__(256,8): pins 8 waves/SIMD -> 8 blocks/CU resident AND
// caps VGPR at 64 (4-deep chains need ~45). Body: 4 INDEPENDENT row chains
// per wave, all 4 loads issued before any consumer -> 4 outstanding 784B
// loads/wave = 100KB/CU in flight, slack even at loaded (queuing) latency.
__global__ __launch_bounds__(256, 8) void k_logits(const float* __restrict__ kb,
                                                   const float* __restrict__ gpart,
                                                   const float* __restrict__ mem,
                                                   const float* __restrict__ ctrl,
                                                   const float* __restrict__ w_attn,
                                                   float* __restrict__ rai_part) {
    __shared__ float p_s[64];
    __shared__ float part[4][S];
    const int bid = blockIdx.x;
    const int b = bid >> 3, c = bid & 7;
    const int t = threadIdx.x;
    const int w = t >> 6, l = t & 63;
    if (t < 64) {
        const int d = c * 64 + t;
        float s = 0.f;
#pragma unroll
        for (int ce = 0; ce < NCH; ++ce)
            s += gpart[((size_t)b * NCH + ce) * D + d];
        p_s[t] = mem[b * D + d] * s + ctrl[b * D + d] * w_attn[d];
    }
    __syncthreads();
    const float* base = kb + (size_t)b * D * S + (size_t)c * 64 * S;
    if (l < SQ) {
        float4 acc0 = {0,0,0,0}, acc1 = {0,0,0,0}, acc2 = {0,0,0,0}, acc3 = {0,0,0,0};
#pragma unroll 1
        for (int i = 0; i < 4; ++i) {
            const int r = w * 16 + i;
            const float4 v0 = *(const float4*)(base + (size_t)(r     ) * S + 4 * l);
            const float4 v1 = *(const float4*)(base + (size_t)(r +  4) * S + 4 * l);
            const float4 v2 = *(const float4*)(base + (size_t)(r +  8) * S + 4 * l);
            const float4 v3 = *(const float4*)(base + (size_t)(r + 12) * S + 4 * l);
            const float p0 = p_s[r], p1 = p_s[r + 4], p2 = p_s[r + 8], p3 = p_s[r + 12];
            acc0.x += p0 * v0.x; acc0.y += p0 * v0.y; acc0.z += p0 * v0.z; acc0.w += p0 * v0.w;
            acc1.x += p1 * v1.x; acc1.y += p1 * v1.y; acc1.z += p1 * v1.z; acc1.w += p1 * v1.w;
            acc2.x += p2 * v2.x; acc2.y += p2 * v2.y; acc2.z += p2 * v2.z; acc2.w += p2 * v2.w;
            acc3.x += p3 * v3.x; acc3.y += p3 * v3.y; acc3.z += p3 * v3.z; acc3.w += p3 * v3.w;
        }
        part[w][4 * l + 0] = (acc0.x + acc1.x) + (acc2.x + acc3.x);
        part[w][4 * l + 1] = (acc0.y + acc1.y) + (acc2.y + acc3.y);
        part[w][4 * l + 2] = (acc0.z + acc1.z) + (acc2.z + acc3.z);
        part[w][4 * l + 3] = (acc0.w + acc1.w) + (acc2.w + acc3.w);
    }
    __syncthreads();
    if (t < S)
        rai_part[(size_t)bid * S + t] = (part[0][t] + part[1][t]) + (part[2][t] + part[3][t]);
}

// ---------------- K3: softmax-head + weighted sum. Grid B*8 = 2048 x 256.
// Same 4-deep independent chains; ALL loads of a 4-row group issue before the
// shuffle-reduce of that group (R6 reduced every 2 rows -> wave stalled on
// vmcnt before shuffles, serializing the stream).
__global__ __launch_bounds__(256, 8) void k_wsum(const float* __restrict__ kb,
                                                 const float* __restrict__ rai_part,
                                                 float* __restrict__ out) {
    __shared__ float rvi_s[S];
    __shared__ float redm[4], reds[4];
    const int bid = blockIdx.x;
    const int b = bid >> 3, c = bid & 7;
    const int t = threadIdx.x;
    const int w = t >> 6, l = t & 63;
    float rai = -INFINITY;
    if (t < S) {
        float v = 0.f;
#pragma unroll
        for (int k = 0; k < NCH; ++k)
            v += rai_part[((size_t)b * NCH + k) * S + t];
        rai = v;
    }
    float m = rai;
#pragma unroll
    for (int o = 1; o < 64; o <<= 1) m = fmaxf(m, __shfl_xor(m, o, 64));
    if (l == 0) redm[w] = m;
    __syncthreads();
    m = fmaxf(fmaxf(redm[0], redm[1]), fmaxf(redm[2], redm[3]));
    float ex = (t < S) ? __expf(rai - m) : 0.f;
    float sm = ex;
#pragma unroll
    for (int o = 1; o < 64; o <<= 1) sm += __shfl_xor(sm, o, 64);
    if (l == 0) reds[w] = sm;
    __syncthreads();
    const float li = (reds[0] + reds[1]) + (reds[2] + reds[3]);
    if (t < S) rvi_s[t] = ex / li;
    __syncthreads();

    float4 rv = {0.f, 0.f, 0.f, 0.f};
    if (l < SQ) rv = *(const float4*)&rvi_s[4 * l];
    const float* base = kb + (size_t)b * D * S + (size_t)c * 64 * S;
#pragma unroll 1
    for (int i = 0; i < 4; ++i) {
        const int r = w * 16 + i;
        float a0 = 0.f, a1 = 0.f, a2 = 0.f, a3 = 0.f;
        if (l < SQ) {
            const float4 v0 = *(const float4*)(base + (size_t)(r     ) * S + 4 * l);
            const float4 v1 = *(const float4*)(base + (size_t)(r +  4) * S + 4 * l);
            const float4 v2 = *(const float4*)(base + (size_t)(r +  8) * S + 4 * l);
            const float4 v3 = *(const float4*)(base + (size_t)(r + 12) * S + 4 * l);
            a0 = rv.x * v0.x + rv.y * v0.y + rv.z * v0.z + rv.w * v0.w;
            a1 = rv.x * v1.x + rv.y * v1.y + rv.z * v1.z + rv.w * v1.w;
            a2 = rv.x * v2.x + rv.y * v2.y + rv.z * v2.z + rv.w * v2.w;
            a3 = rv.x * v3.x + rv.y * v3.y + rv.z * v3.z + rv.w * v3.w;
        }
#pragma unroll
        for (int o = 1; o < 64; o <<= 1) {
            a0 += __shfl_xor(a0, o, 64);
            a1 += __shfl_xor(a1, o, 64);
            a2 += __shfl_xor(a2, o, 64);
            a3 += __shfl_xor(a3, o, 64);
        }
        if (l == 0) {
            float* ob = out + (size_t)b * D + c * 64;
            ob[r] = a0; ob[r + 4] = a1; ob[r + 8] = a2; ob[r + 12] = a3;
        }
    }
}

extern "C" void kernel_launch(void* const* d_in, const int* in_sizes, int n_in,
                              void* d_out, int out_size, void* d_ws, size_t ws_size,
                              hipStream_t stream) {
    const float* mem  = (const float*)d_in[0];  // [B, d]
    const float* ctrl = (const float*)d_in[1];  // [B, d]
    const float* kb   = (const float*)d_in[2];  // [B, d, S]
    const float* W    = (const float*)d_in[3];  // [d, d]
    // d_in[4] = b_concat: softmax-invariant, unused
    const float* wat  = (const float*)d_in[5];  // [d]
    float* out = (float*)d_out;                 // [B, d]

    float* gpart    = (float*)d_ws;                      // B*8*D = 4 MB
    float* rai_part = gpart + (size_t)B * NCH * D;       // 2048*S = 1.6 MB

    k_gemm  <<<256,     256, 0, stream>>>(ctrl, wat, W, gpart);
    k_logits<<<B * NCH, 256, 0, stream>>>(kb, gpart, mem, ctrl, wat, rai_part);
    k_wsum  <<<B * NCH, 256, 0, stream>>>(kb, rai_part, out);
}